// Round 2
// baseline (2814.112 us; speedup 1.0000x reference)
//
#include <hip/hip_runtime.h>

// ============================================================================
// TemporalPointNet (PointNet++ style) forward on MI355X.
// B=2, T=4 -> BT=8 "batches", N=4096 points, 4 coords (xyz + t).
// SA1: npoint=512, r=0.2, K=32, C_in=4,  MLP 64,64,128
// SA2: npoint=128, r=0.4, K=64, C_in=131, MLP 128,128,256
// SA3: group_all,          K=128, C_in=259, MLP 256,512,1024
// Output: (2,4,1024) f32 = 8192 floats.
//
// Round-2 hardening: the harness poisons d_ws to 0xAA before every timed
// launch; call 1 (which validated) saw different initial ws contents. To make
// every call bit-identical to call 1 we (a) zero the whole used ws region up
// front, (b) replace atomicAdd-based BN stats with a deterministic two-stage
// reduction, (c) clamp all gathered indices (JAX gather clamps OOB anyway).
// ============================================================================

// ---------------- FPS: one block per batch ----------------
// Matches jnp semantics: dist init 1e10, d = ((dx^2+dy^2)+dz^2) with rn ops
// (no fma contraction), argmax picks FIRST occurrence of max (lowest index).
template<int BLOCK, int ITEMS>
__global__ __launch_bounds__(BLOCK) void fps_kernel(
    const float* __restrict__ pts, int stride, int N, int npoint,
    int* __restrict__ outIdx, float* __restrict__ outXyz)
{
    extern __shared__ float smem[];
    float* sx = smem;
    float* sy = smem + N;
    float* sz = smem + 2 * N;
    __shared__ float rv[BLOCK / 64];
    __shared__ int   ri[BLOCK / 64];
    __shared__ int   s_far;

    const int b = blockIdx.x;
    const int tid = threadIdx.x;
    const float* P = pts + (size_t)b * N * stride;

    float dloc[ITEMS];
#pragma unroll
    for (int w = 0; w < ITEMS; ++w) {
        int n = tid + w * BLOCK;
        if (n < N) {
            sx[n] = P[(size_t)n * stride + 0];
            sy[n] = P[(size_t)n * stride + 1];
            sz[n] = P[(size_t)n * stride + 2];
        }
        dloc[w] = 1e10f;
    }
    __syncthreads();

    int far = 0;
    for (int i = 0; i < npoint; ++i) {
        if (tid == 0) {
            outIdx[(size_t)b * npoint + i] = far;
            outXyz[((size_t)b * npoint + i) * 3 + 0] = sx[far];
            outXyz[((size_t)b * npoint + i) * 3 + 1] = sy[far];
            outXyz[((size_t)b * npoint + i) * 3 + 2] = sz[far];
        }
        const float cx = sx[far], cy = sy[far], cz = sz[far];
        float bestV = -1.0f;
        int   bestI = 0x7fffffff;
#pragma unroll
        for (int w = 0; w < ITEMS; ++w) {
            int n = tid + w * BLOCK;
            if (n < N) {
                float dx = __fsub_rn(sx[n], cx);
                float dy = __fsub_rn(sy[n], cy);
                float dz = __fsub_rn(sz[n], cz);
                float d = __fadd_rn(__fadd_rn(__fmul_rn(dx, dx), __fmul_rn(dy, dy)),
                                    __fmul_rn(dz, dz));
                float dd = fminf(dloc[w], d);
                dloc[w] = dd;
                if (dd > bestV) { bestV = dd; bestI = n; }  // n ascending -> first max kept
            }
        }
        // wave argmax (lowest index on tie)
#pragma unroll
        for (int off = 32; off > 0; off >>= 1) {
            float ov = __shfl_down(bestV, off);
            int   oi = __shfl_down(bestI, off);
            if (ov > bestV || (ov == bestV && oi < bestI)) { bestV = ov; bestI = oi; }
        }
        if ((tid & 63) == 0) { rv[tid >> 6] = bestV; ri[tid >> 6] = bestI; }
        __syncthreads();
        if (tid == 0) {
            float v = rv[0]; int bi = ri[0];
#pragma unroll
            for (int k = 1; k < BLOCK / 64; ++k)
                if (rv[k] > v || (rv[k] == v && ri[k] < bi)) { v = rv[k]; bi = ri[k]; }
            s_far = bi;
        }
        __syncthreads();
        far = s_far;
    }
}

// ---------------- query_ball: one wave per center ----------------
// First nsample indices (ascending) with d2 <= r2; pad with first hit.
__global__ __launch_bounds__(256) void query_ball_kernel(
    const float* __restrict__ xyz, int stride, int N,
    const float* __restrict__ centers, int nCenters, int S,
    float r2, int nsample, int* __restrict__ outIdx)
{
    int gw = (blockIdx.x * 256 + threadIdx.x) >> 6;
    int lane = threadIdx.x & 63;
    if (gw >= nCenters) return;
    int b = gw / S;
    const float* P = xyz + (size_t)b * N * stride;
    float cx = centers[(size_t)gw * 3 + 0];
    float cy = centers[(size_t)gw * 3 + 1];
    float cz = centers[(size_t)gw * 3 + 2];
    int* out = outIdx + (size_t)gw * nsample;
    int cnt = 0;
    int firstIdx = 0;   // cnt>=1 always (center is one of the points); 0 is a safe default
    bool haveFirst = false;
    for (int base = 0; base < N && cnt < nsample; base += 64) {
        int n = base + lane;
        bool inb = false;
        if (n < N) {
            float dx = __fsub_rn(cx, P[(size_t)n * stride + 0]);
            float dy = __fsub_rn(cy, P[(size_t)n * stride + 1]);
            float dz = __fsub_rn(cz, P[(size_t)n * stride + 2]);
            float d = __fadd_rn(__fadd_rn(__fmul_rn(dx, dx), __fmul_rn(dy, dy)),
                                __fmul_rn(dz, dz));
            inb = !(d > r2);
        }
        unsigned long long mask = __ballot(inb);
        if (mask) {
            if (!haveFirst) { firstIdx = base + __builtin_ctzll(mask); haveFirst = true; }
            if (inb) {
                int pos = cnt + __builtin_popcountll(mask & ((1ull << lane) - 1ull));
                if (pos < nsample) out[pos] = n;
            }
            cnt += (int)__builtin_popcountll(mask);
        }
    }
    if (cnt > nsample) cnt = nsample;
    for (int p = cnt + lane; p < nsample; p += 64) out[p] = firstIdx;
}

// ---------------- grouping kernels ----------------
// grouped1: (8*512*32, 4) = [xyz - center, t]
__global__ __launch_bounds__(256) void group1_kernel(
    const float* __restrict__ in, const int* __restrict__ qb,
    const float* __restrict__ ctr, float* __restrict__ out)
{
    int i = blockIdx.x * 256 + threadIdx.x;
    if (i >= 8 * 512 * 32) return;
    int bs = i / 32;           // b*512+s
    int b = i / (512 * 32);
    int idx = qb[i];
    idx = (idx < 0) ? 0 : (idx > 4095 ? 4095 : idx);   // JAX-style clamp
    const float* p = in + ((size_t)b * 4096 + idx) * 4;
    const float* c = ctr + (size_t)bs * 3;
    float* o = out + (size_t)i * 4;
    o[0] = __fsub_rn(p[0], c[0]);
    o[1] = __fsub_rn(p[1], c[1]);
    o[2] = __fsub_rn(p[2], c[2]);
    o[3] = p[3];
}

// grouped2: (8*128*64, 131) = [xyz - center (3), feat1 (128)]
__global__ __launch_bounds__(256) void group2_kernel(
    const float* __restrict__ xyz /*(8*512,3)*/, const float* __restrict__ feat /*(8*512,128)*/,
    const int* __restrict__ qb /*(8*128*64)*/, const float* __restrict__ ctr /*(8*128,3)*/,
    float* __restrict__ out)
{
    int i = blockIdx.x * 256 + threadIdx.x;
    if (i >= 65536 * 131) return;
    int sk = i / 131;
    int c = i - sk * 131;
    int b = sk / (128 * 64);
    int bs = sk / 64;
    int idx = qb[sk];
    idx = (idx < 0) ? 0 : (idx > 511 ? 511 : idx);     // JAX-style clamp
    float v;
    if (c < 3) v = __fsub_rn(xyz[((size_t)b * 512 + idx) * 3 + c], ctr[(size_t)bs * 3 + c]);
    else       v = feat[((size_t)b * 512 + idx) * 128 + (c - 3)];
    out[i] = v;
}

// grouped3: (8*128, 259) = [new_xyz2 (3, NOT recentered), feat2 (256)]
__global__ __launch_bounds__(256) void group3_kernel(
    const float* __restrict__ ctr2 /*(8*128,3)*/, const float* __restrict__ feat2 /*(8*128,256)*/,
    float* __restrict__ out)
{
    int i = blockIdx.x * 256 + threadIdx.x;
    if (i >= 1024 * 259) return;
    int sk = i / 259;
    int c = i - sk * 259;
    out[i] = (c < 3) ? ctr2[(size_t)sk * 3 + c] : feat2[(size_t)sk * 256 + (c - 3)];
}

// ---------------- GEMM: Y[M,O] = act(X[M,C]) * W[O,C]^T ----------------
// act(x) = applyAct ? relu(x*scale[c]+shift[c]) : x   (BN of PREVIOUS layer)
__global__ __launch_bounds__(256) void gemm_bn(
    const float* __restrict__ X, const float* __restrict__ W,
    float* __restrict__ Y,
    const float* __restrict__ scale, const float* __restrict__ shift,
    int applyAct, int M, int C, int O)
{
    __shared__ float Xs[16][65];
    __shared__ float Ws[16][65];
    const int m0 = blockIdx.x * 64;
    const int o0 = blockIdx.y * 64;
    const int tid = threadIdx.x;
    const int tx = tid & 15;
    const int ty = tid >> 4;
    float acc[4][4] = {};
    for (int k0 = 0; k0 < C; k0 += 16) {
        for (int l = tid; l < 64 * 16; l += 256) {
            int r = l >> 4, kk = l & 15;
            int c = k0 + kk;
            float v = 0.f;
            if (c < C) {
                v = X[(size_t)(m0 + r) * C + c];
                if (applyAct) v = fmaxf(v * scale[c] + shift[c], 0.f);
            }
            Xs[kk][r] = v;
        }
        for (int l = tid; l < 64 * 16; l += 256) {
            int r = l >> 4, kk = l & 15;
            int c = k0 + kk;
            Ws[kk][r] = (c < C) ? W[(size_t)(o0 + r) * C + c] : 0.f;
        }
        __syncthreads();
#pragma unroll
        for (int kk = 0; kk < 16; ++kk) {
            float a[4], bv[4];
#pragma unroll
            for (int i = 0; i < 4; ++i) a[i] = Xs[kk][ty * 4 + i];
#pragma unroll
            for (int j = 0; j < 4; ++j) bv[j] = Ws[kk][tx * 4 + j];
#pragma unroll
            for (int i = 0; i < 4; ++i)
#pragma unroll
                for (int j = 0; j < 4; ++j)
                    acc[i][j] += a[i] * bv[j];
        }
        __syncthreads();
    }
#pragma unroll
    for (int i = 0; i < 4; ++i) {
        int m = m0 + ty * 4 + i;
#pragma unroll
        for (int j = 0; j < 4; ++j) {
            int o = o0 + tx * 4 + j;
            Y[(size_t)m * O + o] = acc[i][j];
        }
    }
}

// ---------------- per-channel partial sum / sumsq (deterministic) ----------
// part[o*YB + yb] = sum over rows in y-block yb; part[O*YB + o*YB + yb] = sumsq
__global__ __launch_bounds__(256) void stats_partial(
    const float* __restrict__ Y, double* __restrict__ part, int M, int O, int YB)
{
    int olane = threadIdx.x & 63;
    int mlane = threadIdx.x >> 6;            // 0..3
    int o = blockIdx.x * 64 + olane;
    int yb = blockIdx.y;
    int mbase = yb * 1024;
    int mend = min(M, mbase + 1024);
    double s = 0.0, s2 = 0.0;
    for (int m = mbase + mlane; m < mend; m += 4) {
        float v = Y[(size_t)m * O + o];
        s += (double)v;
        s2 += (double)v * (double)v;
    }
    __shared__ double sd[512];
    sd[threadIdx.x] = s;
    sd[256 + threadIdx.x] = s2;
    __syncthreads();
    if (mlane == 0) {
        double t  = sd[olane] + sd[64 + olane] + sd[128 + olane] + sd[192 + olane];
        double t2 = sd[256 + olane] + sd[320 + olane] + sd[384 + olane] + sd[448 + olane];
        part[(size_t)o * YB + yb] = t;
        part[(size_t)O * YB + (size_t)o * YB + yb] = t2;
    }
}

// ---------------- finalize BN: scale = g*rsqrt(var+eps), shift = b - mean*scale
__global__ __launch_bounds__(256) void finalize_bn(
    const double* __restrict__ part, const float* __restrict__ g,
    const float* __restrict__ bb, float* __restrict__ scale,
    float* __restrict__ shift, int O, int YB, double invM)
{
    int o = blockIdx.x * 256 + threadIdx.x;
    if (o >= O) return;
    double s = 0.0, s2 = 0.0;
    for (int yb = 0; yb < YB; ++yb) {
        s  += part[(size_t)o * YB + yb];
        s2 += part[(size_t)O * YB + (size_t)o * YB + yb];
    }
    double mean = s * invM;
    double var = s2 * invM - mean * mean;
    float varf = (float)var;
    if (varf < 0.f) varf = 0.f;
    float sc = g[o] * rsqrtf(varf + 1e-5f);
    float sh = bb[o] - (float)mean * sc;
    scale[o] = sc;
    shift[o] = sh;
}

// ---------------- BN + ReLU + max over K ----------------
__global__ __launch_bounds__(256) void bn_relu_max(
    const float* __restrict__ Y, const float* __restrict__ scale,
    const float* __restrict__ shift, float* __restrict__ out,
    int Stot, int K, int O)
{
    int idx = blockIdx.x * 256 + threadIdx.x;
    if (idx >= Stot * O) return;
    int s = idx / O;
    int o = idx - s * O;
    const float* base = Y + (size_t)s * K * O + o;
    float sc = scale[o], sh = shift[o];
    float mx = 0.f;  // relu values are >= 0, max over K >= 0
    for (int k = 0; k < K; ++k) {
        float v = base[(size_t)k * O] * sc + sh;
        v = fmaxf(v, 0.f);
        mx = fmaxf(mx, v);
    }
    out[idx] = mx;
}

// ============================================================================
extern "C" void kernel_launch(void* const* d_in, const int* in_sizes, int n_in,
                              void* d_out, int out_size, void* d_ws, size_t ws_size,
                              hipStream_t stream)
{
    const float* xin = (const float*)d_in[0];
    const float* w[9]; const float* g[9]; const float* bb[9];
    for (int i = 0; i < 9; ++i) {
        w[i]  = (const float*)d_in[1 + 3 * i];
        g[i]  = (const float*)d_in[2 + 3 * i];
        bb[i] = (const float*)d_in[3 + 3 * i];
    }

    char* base = (char*)d_ws;
    size_t off = 0;
    auto alloc = [&](size_t bytes) -> void* {
        void* p = base + off;
        off = (off + bytes + 255) & ~(size_t)255;
        return p;
    };
    int*    fps1   = (int*)alloc((size_t)4096 * 4);
    int*    qb1    = (int*)alloc((size_t)131072 * 4);
    int*    fps2   = (int*)alloc((size_t)1024 * 4);
    int*    qb2    = (int*)alloc((size_t)65536 * 4);
    float*  nx1    = (float*)alloc((size_t)12288 * 4);   // (8*512,3)
    float*  nx2    = (float*)alloc((size_t)3072 * 4);    // (8*128,3)
    float*  feat1  = (float*)alloc((size_t)524288 * 4);  // (8*512,128)
    float*  feat2  = (float*)alloc((size_t)262144 * 4);  // (8*128,256)
    double* part   = (double*)alloc((size_t)65536 * 8);  // 2*O*YB doubles, max 32768
    float*  scales = (float*)alloc((size_t)9 * 1024 * 4);
    float*  shifts = (float*)alloc((size_t)9 * 1024 * 4);
    float*  A      = (float*)alloc((size_t)16777216 * 4); // ping (131072x128 / 65536x256)
    float*  BG     = (float*)alloc((size_t)8585216 * 4);  // pong (65536x131 max)
    if (off > ws_size) return;  // workspace too small; visible as absmax failure

    // Make every call bit-identical to the first (validated) call regardless
    // of harness poison: zero the entire used workspace region up front.
    hipMemsetAsync(d_ws, 0, off, stream);

    // ---------------- SA1 ----------------
    fps_kernel<1024, 4><<<8, 1024, 3 * 4096 * 4, stream>>>(xin, 4, 4096, 512, fps1, nx1);
    query_ball_kernel<<<(8 * 512 * 64) / 256, 256, 0, stream>>>(
        xin, 4, 4096, nx1, 8 * 512, 512, 0.04f, 32, qb1);
    group1_kernel<<<131072 / 256, 256, 0, stream>>>(xin, qb1, nx1, BG);

    // L1_0: (131072,4) -> 64
    gemm_bn<<<dim3(131072 / 64, 1), 256, 0, stream>>>(BG, w[0], A, nullptr, nullptr, 0, 131072, 4, 64);
    stats_partial<<<dim3(1, 128), 256, 0, stream>>>(A, part, 131072, 64, 128);
    finalize_bn<<<1, 256, 0, stream>>>(part, g[0], bb[0], scales + 0 * 1024, shifts + 0 * 1024, 64, 128, 1.0 / 131072.0);
    // L1_1: 64 -> 64
    gemm_bn<<<dim3(131072 / 64, 1), 256, 0, stream>>>(A, w[1], BG, scales + 0 * 1024, shifts + 0 * 1024, 1, 131072, 64, 64);
    stats_partial<<<dim3(1, 128), 256, 0, stream>>>(BG, part, 131072, 64, 128);
    finalize_bn<<<1, 256, 0, stream>>>(part, g[1], bb[1], scales + 1 * 1024, shifts + 1 * 1024, 64, 128, 1.0 / 131072.0);
    // L1_2: 64 -> 128
    gemm_bn<<<dim3(131072 / 64, 2), 256, 0, stream>>>(BG, w[2], A, scales + 1 * 1024, shifts + 1 * 1024, 1, 131072, 64, 128);
    stats_partial<<<dim3(2, 128), 256, 0, stream>>>(A, part, 131072, 128, 128);
    finalize_bn<<<1, 256, 0, stream>>>(part, g[2], bb[2], scales + 2 * 1024, shifts + 2 * 1024, 128, 128, 1.0 / 131072.0);
    bn_relu_max<<<(4096 * 128) / 256, 256, 0, stream>>>(A, scales + 2 * 1024, shifts + 2 * 1024, feat1, 4096, 32, 128);

    // ---------------- SA2 ----------------
    fps_kernel<512, 1><<<8, 512, 3 * 512 * 4, stream>>>(nx1, 3, 512, 128, fps2, nx2);
    query_ball_kernel<<<(8 * 128 * 64) / 256, 256, 0, stream>>>(
        nx1, 3, 512, nx2, 8 * 128, 128, 0.16f, 64, qb2);
    group2_kernel<<<(65536 * 131) / 256, 256, 0, stream>>>(nx1, feat1, qb2, nx2, BG);

    // L2_0: (65536,131) -> 128
    gemm_bn<<<dim3(65536 / 64, 2), 256, 0, stream>>>(BG, w[3], A, nullptr, nullptr, 0, 65536, 131, 128);
    stats_partial<<<dim3(2, 64), 256, 0, stream>>>(A, part, 65536, 128, 64);
    finalize_bn<<<1, 256, 0, stream>>>(part, g[3], bb[3], scales + 3 * 1024, shifts + 3 * 1024, 128, 64, 1.0 / 65536.0);
    // L2_1: 128 -> 128
    gemm_bn<<<dim3(65536 / 64, 2), 256, 0, stream>>>(A, w[4], BG, scales + 3 * 1024, shifts + 3 * 1024, 1, 65536, 128, 128);
    stats_partial<<<dim3(2, 64), 256, 0, stream>>>(BG, part, 65536, 128, 64);
    finalize_bn<<<1, 256, 0, stream>>>(part, g[4], bb[4], scales + 4 * 1024, shifts + 4 * 1024, 128, 64, 1.0 / 65536.0);
    // L2_2: 128 -> 256
    gemm_bn<<<dim3(65536 / 64, 4), 256, 0, stream>>>(BG, w[5], A, scales + 4 * 1024, shifts + 4 * 1024, 1, 65536, 128, 256);
    stats_partial<<<dim3(4, 64), 256, 0, stream>>>(A, part, 65536, 256, 64);
    finalize_bn<<<1, 256, 0, stream>>>(part, g[5], bb[5], scales + 5 * 1024, shifts + 5 * 1024, 256, 64, 1.0 / 65536.0);
    bn_relu_max<<<(1024 * 256) / 256, 256, 0, stream>>>(A, scales + 5 * 1024, shifts + 5 * 1024, feat2, 1024, 64, 256);

    // ---------------- SA3 (group_all) ----------------
    group3_kernel<<<(1024 * 259 + 255) / 256, 256, 0, stream>>>(nx2, feat2, BG);

    // L3_0: (1024,259) -> 256
    gemm_bn<<<dim3(1024 / 64, 4), 256, 0, stream>>>(BG, w[6], A, nullptr, nullptr, 0, 1024, 259, 256);
    stats_partial<<<dim3(4, 1), 256, 0, stream>>>(A, part, 1024, 256, 1);
    finalize_bn<<<1, 256, 0, stream>>>(part, g[6], bb[6], scales + 6 * 1024, shifts + 6 * 1024, 256, 1, 1.0 / 1024.0);
    // L3_1: 256 -> 512
    gemm_bn<<<dim3(1024 / 64, 8), 256, 0, stream>>>(A, w[7], BG, scales + 6 * 1024, shifts + 6 * 1024, 1, 1024, 256, 512);
    stats_partial<<<dim3(8, 1), 256, 0, stream>>>(BG, part, 1024, 512, 1);
    finalize_bn<<<2, 256, 0, stream>>>(part, g[7], bb[7], scales + 7 * 1024, shifts + 7 * 1024, 512, 1, 1.0 / 1024.0);
    // L3_2: 512 -> 1024
    gemm_bn<<<dim3(1024 / 64, 16), 256, 0, stream>>>(BG, w[8], A, scales + 7 * 1024, shifts + 7 * 1024, 1, 1024, 512, 1024);
    stats_partial<<<dim3(16, 1), 256, 0, stream>>>(A, part, 1024, 1024, 1);
    finalize_bn<<<4, 256, 0, stream>>>(part, g[8], bb[8], scales + 8 * 1024, shifts + 8 * 1024, 1024, 1, 1.0 / 1024.0);
    bn_relu_max<<<(8 * 1024) / 256, 256, 0, stream>>>(A, scales + 8 * 1024, shifts + 8 * 1024, (float*)d_out, 8, 128, 1024);
}

// Round 3
// 2260.666 us; speedup vs baseline: 1.2448x; 1.2448x over previous
//
#include <hip/hip_runtime.h>

// ============================================================================
// TemporalPointNet (PointNet++ style) forward on MI355X.
// B=2, T=4 -> BT=8 "batches", N=4096 points, 4 coords (xyz + t).
// SA1: npoint=512, r=0.2, K=32, C_in=4,  MLP 64,64,128
// SA2: npoint=128, r=0.4, K=64, C_in=131, MLP 128,128,256
// SA3: group_all,          K=128, C_in=259, MLP 256,512,1024
// Output: (2,4,1024) f32 = 8192 floats.
//
// R3: FPS rewritten latency-first (coords in VGPRs, single barrier/iter,
// reduction carries winner coords); GEMM BK=32 + aligned ds_read_b128.
// ============================================================================

// ---------------- FPS: one block (256 thr, 4 waves) per batch ----------------
// Point n owned by thread (n & 255), item (n >> 8). Matches jnp semantics:
// dist init 1e10, d = ((dx^2+dy^2)+dz^2) with rn ops (no fma contraction),
// argmax picks FIRST occurrence of max (lowest index on ties).
template<int ITEMS, int STRIDE>
__global__ __launch_bounds__(256) void fps_fast(
    const float* __restrict__ pts, int npoint,
    int* __restrict__ outIdx, float* __restrict__ outXyz)
{
    constexpr int N = ITEMS * 256;
    __shared__ float wred[2][4][8];   // [parity][wave][v, idx, x, y, z, ...]
    __shared__ float c0[3];

    const int b = blockIdx.x;
    const int tid = threadIdx.x;
    const int wid = tid >> 6;
    const int lane = tid & 63;
    const float* P = pts + (size_t)b * N * STRIDE;

    float px[ITEMS], py[ITEMS], pz[ITEMS], dloc[ITEMS];
#pragma unroll
    for (int w = 0; w < ITEMS; ++w) {
        int n = tid + (w << 8);
        if (STRIDE == 4) {
            float4 v = *(const float4*)(P + (size_t)n * 4);
            px[w] = v.x; py[w] = v.y; pz[w] = v.z;
        } else {
            px[w] = P[(size_t)n * STRIDE + 0];
            py[w] = P[(size_t)n * STRIDE + 1];
            pz[w] = P[(size_t)n * STRIDE + 2];
        }
        dloc[w] = 1e10f;
    }
    if (tid == 0) { c0[0] = px[0]; c0[1] = py[0]; c0[2] = pz[0]; }
    __syncthreads();
    float cx = c0[0], cy = c0[1], cz = c0[2];
    int far = 0;

    for (int i = 0; i < npoint; ++i) {
        if (tid == 0) {
            outIdx[(size_t)b * npoint + i] = far;
            outXyz[((size_t)b * npoint + i) * 3 + 0] = cx;
            outXyz[((size_t)b * npoint + i) * 3 + 1] = cy;
            outXyz[((size_t)b * npoint + i) * 3 + 2] = cz;
        }
        float bestV = -1.0f;
        int   bestI = 0x7fffffff;
        float bx = 0.f, by = 0.f, bz = 0.f;
#pragma unroll
        for (int w = 0; w < ITEMS; ++w) {
            float dx = __fsub_rn(px[w], cx);
            float dy = __fsub_rn(py[w], cy);
            float dz = __fsub_rn(pz[w], cz);
            float d = __fadd_rn(__fadd_rn(__fmul_rn(dx, dx), __fmul_rn(dy, dy)),
                                __fmul_rn(dz, dz));
            float dd = fminf(dloc[w], d);
            dloc[w] = dd;
            // strict > : keeps lowest w (= lowest global index) on ties
            if (dd > bestV) { bestV = dd; bestI = tid + (w << 8);
                              bx = px[w]; by = py[w]; bz = pz[w]; }
        }
        // 64-lane butterfly argmax carrying winner coords (lowest idx on tie)
#pragma unroll
        for (int off = 1; off < 64; off <<= 1) {
            float ov = __shfl_xor(bestV, off);
            int   oi = __shfl_xor(bestI, off);
            float ox = __shfl_xor(bx, off);
            float oy = __shfl_xor(by, off);
            float oz = __shfl_xor(bz, off);
            if (ov > bestV || (ov == bestV && oi < bestI)) {
                bestV = ov; bestI = oi; bx = ox; by = oy; bz = oz;
            }
        }
        const int par = i & 1;
        if (lane == 0) {
            wred[par][wid][0] = bestV;
            wred[par][wid][1] = __int_as_float(bestI);
            wred[par][wid][2] = bx;
            wred[par][wid][3] = by;
            wred[par][wid][4] = bz;
        }
        __syncthreads();   // single barrier per iteration (parity dbuf on wred)
        bestV = wred[par][0][0];
        bestI = __float_as_int(wred[par][0][1]);
        bx = wred[par][0][2]; by = wred[par][0][3]; bz = wred[par][0][4];
#pragma unroll
        for (int k2 = 1; k2 < 4; ++k2) {
            float v = wred[par][k2][0];
            int  ii = __float_as_int(wred[par][k2][1]);
            if (v > bestV || (v == bestV && ii < bestI)) {
                bestV = v; bestI = ii;
                bx = wred[par][k2][2]; by = wred[par][k2][3]; bz = wred[par][k2][4];
            }
        }
        far = bestI; cx = bx; cy = by; cz = bz;
    }
}

// ---------------- query_ball: one wave per center ----------------
// First nsample indices (ascending) with d2 <= r2; pad with first hit.
__global__ __launch_bounds__(256) void query_ball_kernel(
    const float* __restrict__ xyz, int stride, int N,
    const float* __restrict__ centers, int nCenters, int S,
    float r2, int nsample, int* __restrict__ outIdx)
{
    int gw = (blockIdx.x * 256 + threadIdx.x) >> 6;
    int lane = threadIdx.x & 63;
    if (gw >= nCenters) return;
    int b = gw / S;
    const float* P = xyz + (size_t)b * N * stride;
    float cx = centers[(size_t)gw * 3 + 0];
    float cy = centers[(size_t)gw * 3 + 1];
    float cz = centers[(size_t)gw * 3 + 2];
    int* out = outIdx + (size_t)gw * nsample;
    int cnt = 0;
    int firstIdx = 0;
    bool haveFirst = false;
    for (int base = 0; base < N && cnt < nsample; base += 64) {
        int n = base + lane;
        bool inb = false;
        if (n < N) {
            float dx = __fsub_rn(cx, P[(size_t)n * stride + 0]);
            float dy = __fsub_rn(cy, P[(size_t)n * stride + 1]);
            float dz = __fsub_rn(cz, P[(size_t)n * stride + 2]);
            float d = __fadd_rn(__fadd_rn(__fmul_rn(dx, dx), __fmul_rn(dy, dy)),
                                __fmul_rn(dz, dz));
            inb = !(d > r2);
        }
        unsigned long long mask = __ballot(inb);
        if (mask) {
            if (!haveFirst) { firstIdx = base + __builtin_ctzll(mask); haveFirst = true; }
            if (inb) {
                int pos = cnt + __builtin_popcountll(mask & ((1ull << lane) - 1ull));
                if (pos < nsample) out[pos] = n;
            }
            cnt += (int)__builtin_popcountll(mask);
        }
    }
    if (cnt > nsample) cnt = nsample;
    for (int p = cnt + lane; p < nsample; p += 64) out[p] = firstIdx;
}

// ---------------- grouping kernels ----------------
__global__ __launch_bounds__(256) void group1_kernel(
    const float* __restrict__ in, const int* __restrict__ qb,
    const float* __restrict__ ctr, float* __restrict__ out)
{
    int i = blockIdx.x * 256 + threadIdx.x;
    if (i >= 8 * 512 * 32) return;
    int bs = i / 32;
    int b = i / (512 * 32);
    int idx = qb[i];
    idx = (idx < 0) ? 0 : (idx > 4095 ? 4095 : idx);
    const float* p = in + ((size_t)b * 4096 + idx) * 4;
    const float* c = ctr + (size_t)bs * 3;
    float* o = out + (size_t)i * 4;
    o[0] = __fsub_rn(p[0], c[0]);
    o[1] = __fsub_rn(p[1], c[1]);
    o[2] = __fsub_rn(p[2], c[2]);
    o[3] = p[3];
}

__global__ __launch_bounds__(256) void group2_kernel(
    const float* __restrict__ xyz, const float* __restrict__ feat,
    const int* __restrict__ qb, const float* __restrict__ ctr,
    float* __restrict__ out)
{
    int i = blockIdx.x * 256 + threadIdx.x;
    if (i >= 65536 * 131) return;
    int sk = i / 131;
    int c = i - sk * 131;
    int b = sk / (128 * 64);
    int bs = sk / 64;
    int idx = qb[sk];
    idx = (idx < 0) ? 0 : (idx > 511 ? 511 : idx);
    float v;
    if (c < 3) v = __fsub_rn(xyz[((size_t)b * 512 + idx) * 3 + c], ctr[(size_t)bs * 3 + c]);
    else       v = feat[((size_t)b * 512 + idx) * 128 + (c - 3)];
    out[i] = v;
}

__global__ __launch_bounds__(256) void group3_kernel(
    const float* __restrict__ ctr2, const float* __restrict__ feat2,
    float* __restrict__ out)
{
    int i = blockIdx.x * 256 + threadIdx.x;
    if (i >= 1024 * 259) return;
    int sk = i / 259;
    int c = i - sk * 259;
    out[i] = (c < 3) ? ctr2[(size_t)sk * 3 + c] : feat2[(size_t)sk * 256 + (c - 3)];
}

// ---------------- GEMM: Y[M,O] = act(X[M,C]) * W[O,C]^T ----------------
// act(x) = applyAct ? relu(x*scale[c]+shift[c]) : x   (BN of PREVIOUS layer)
// 64x64 tile, BK=32, LDS pad 68 floats -> 16B-aligned rows -> ds_read_b128.
// K accumulation order identical to R2 (ascending kk) -> bit-identical output.
__global__ __launch_bounds__(256) void gemm_bn(
    const float* __restrict__ X, const float* __restrict__ W,
    float* __restrict__ Y,
    const float* __restrict__ scale, const float* __restrict__ shift,
    int applyAct, int M, int C, int O)
{
    __shared__ float Xs[32][68];
    __shared__ float Ws[32][68];
    const int m0 = blockIdx.x * 64;
    const int o0 = blockIdx.y * 64;
    const int tid = threadIdx.x;
    const int tx = tid & 15;
    const int ty = tid >> 4;
    float acc[4][4] = {};
    for (int k0 = 0; k0 < C; k0 += 32) {
#pragma unroll
        for (int l8 = 0; l8 < 8; ++l8) {
            int l = tid + l8 * 256;
            int r = l >> 5, kk = l & 31;
            int c = k0 + kk;
            float xv = 0.f, wv = 0.f;
            if (c < C) {
                xv = X[(size_t)(m0 + r) * C + c];
                if (applyAct) xv = fmaxf(xv * scale[c] + shift[c], 0.f);
                wv = W[(size_t)(o0 + r) * C + c];
            }
            Xs[kk][r] = xv;
            Ws[kk][r] = wv;
        }
        __syncthreads();
#pragma unroll
        for (int kk = 0; kk < 32; ++kk) {
            float4 a = *(const float4*)&Xs[kk][ty * 4];
            float4 bv = *(const float4*)&Ws[kk][tx * 4];
            acc[0][0] += a.x * bv.x; acc[0][1] += a.x * bv.y;
            acc[0][2] += a.x * bv.z; acc[0][3] += a.x * bv.w;
            acc[1][0] += a.y * bv.x; acc[1][1] += a.y * bv.y;
            acc[1][2] += a.y * bv.z; acc[1][3] += a.y * bv.w;
            acc[2][0] += a.z * bv.x; acc[2][1] += a.z * bv.y;
            acc[2][2] += a.z * bv.z; acc[2][3] += a.z * bv.w;
            acc[3][0] += a.w * bv.x; acc[3][1] += a.w * bv.y;
            acc[3][2] += a.w * bv.z; acc[3][3] += a.w * bv.w;
        }
        __syncthreads();
    }
#pragma unroll
    for (int i = 0; i < 4; ++i) {
        int m = m0 + ty * 4 + i;
#pragma unroll
        for (int j = 0; j < 4; ++j) {
            int o = o0 + tx * 4 + j;
            Y[(size_t)m * O + o] = acc[i][j];
        }
    }
}

// ---------------- per-channel partial sum / sumsq (deterministic) ----------
__global__ __launch_bounds__(256) void stats_partial(
    const float* __restrict__ Y, double* __restrict__ part, int M, int O, int YB)
{
    int olane = threadIdx.x & 63;
    int mlane = threadIdx.x >> 6;
    int o = blockIdx.x * 64 + olane;
    int yb = blockIdx.y;
    int mbase = yb * 1024;
    int mend = min(M, mbase + 1024);
    double s = 0.0, s2 = 0.0;
    for (int m = mbase + mlane; m < mend; m += 4) {
        float v = Y[(size_t)m * O + o];
        s += (double)v;
        s2 += (double)v * (double)v;
    }
    __shared__ double sd[512];
    sd[threadIdx.x] = s;
    sd[256 + threadIdx.x] = s2;
    __syncthreads();
    if (mlane == 0) {
        double t  = sd[olane] + sd[64 + olane] + sd[128 + olane] + sd[192 + olane];
        double t2 = sd[256 + olane] + sd[320 + olane] + sd[384 + olane] + sd[448 + olane];
        part[(size_t)o * YB + yb] = t;
        part[(size_t)O * YB + (size_t)o * YB + yb] = t2;
    }
}

__global__ __launch_bounds__(256) void finalize_bn(
    const double* __restrict__ part, const float* __restrict__ g,
    const float* __restrict__ bb, float* __restrict__ scale,
    float* __restrict__ shift, int O, int YB, double invM)
{
    int o = blockIdx.x * 256 + threadIdx.x;
    if (o >= O) return;
    double s = 0.0, s2 = 0.0;
    for (int yb = 0; yb < YB; ++yb) {
        s  += part[(size_t)o * YB + yb];
        s2 += part[(size_t)O * YB + (size_t)o * YB + yb];
    }
    double mean = s * invM;
    double var = s2 * invM - mean * mean;
    float varf = (float)var;
    if (varf < 0.f) varf = 0.f;
    float sc = g[o] * rsqrtf(varf + 1e-5f);
    float sh = bb[o] - (float)mean * sc;
    scale[o] = sc;
    shift[o] = sh;
}

__global__ __launch_bounds__(256) void bn_relu_max(
    const float* __restrict__ Y, const float* __restrict__ scale,
    const float* __restrict__ shift, float* __restrict__ out,
    int Stot, int K, int O)
{
    int idx = blockIdx.x * 256 + threadIdx.x;
    if (idx >= Stot * O) return;
    int s = idx / O;
    int o = idx - s * O;
    const float* base = Y + (size_t)s * K * O + o;
    float sc = scale[o], sh = shift[o];
    float mx = 0.f;
    for (int k = 0; k < K; ++k) {
        float v = base[(size_t)k * O] * sc + sh;
        v = fmaxf(v, 0.f);
        mx = fmaxf(mx, v);
    }
    out[idx] = mx;
}

// ============================================================================
extern "C" void kernel_launch(void* const* d_in, const int* in_sizes, int n_in,
                              void* d_out, int out_size, void* d_ws, size_t ws_size,
                              hipStream_t stream)
{
    const float* xin = (const float*)d_in[0];
    const float* w[9]; const float* g[9]; const float* bb[9];
    for (int i = 0; i < 9; ++i) {
        w[i]  = (const float*)d_in[1 + 3 * i];
        g[i]  = (const float*)d_in[2 + 3 * i];
        bb[i] = (const float*)d_in[3 + 3 * i];
    }

    char* base = (char*)d_ws;
    size_t off = 0;
    auto alloc = [&](size_t bytes) -> void* {
        void* p = base + off;
        off = (off + bytes + 255) & ~(size_t)255;
        return p;
    };
    int*    fps1   = (int*)alloc((size_t)4096 * 4);
    int*    qb1    = (int*)alloc((size_t)131072 * 4);
    int*    fps2   = (int*)alloc((size_t)1024 * 4);
    int*    qb2    = (int*)alloc((size_t)65536 * 4);
    float*  nx1    = (float*)alloc((size_t)12288 * 4);
    float*  nx2    = (float*)alloc((size_t)3072 * 4);
    float*  feat1  = (float*)alloc((size_t)524288 * 4);
    float*  feat2  = (float*)alloc((size_t)262144 * 4);
    double* part   = (double*)alloc((size_t)65536 * 8);
    float*  scales = (float*)alloc((size_t)9 * 1024 * 4);
    float*  shifts = (float*)alloc((size_t)9 * 1024 * 4);
    float*  A      = (float*)alloc((size_t)16777216 * 4);
    float*  BG     = (float*)alloc((size_t)8585216 * 4);
    if (off > ws_size) return;

    // Every call must be bit-identical regardless of harness ws poison.
    hipMemsetAsync(d_ws, 0, off, stream);

    // ---------------- SA1 ----------------
    fps_fast<16, 4><<<8, 256, 0, stream>>>(xin, 512, fps1, nx1);
    query_ball_kernel<<<(8 * 512 * 64) / 256, 256, 0, stream>>>(
        xin, 4, 4096, nx1, 8 * 512, 512, 0.04f, 32, qb1);
    group1_kernel<<<131072 / 256, 256, 0, stream>>>(xin, qb1, nx1, BG);

    gemm_bn<<<dim3(131072 / 64, 1), 256, 0, stream>>>(BG, w[0], A, nullptr, nullptr, 0, 131072, 4, 64);
    stats_partial<<<dim3(1, 128), 256, 0, stream>>>(A, part, 131072, 64, 128);
    finalize_bn<<<1, 256, 0, stream>>>(part, g[0], bb[0], scales + 0 * 1024, shifts + 0 * 1024, 64, 128, 1.0 / 131072.0);
    gemm_bn<<<dim3(131072 / 64, 1), 256, 0, stream>>>(A, w[1], BG, scales + 0 * 1024, shifts + 0 * 1024, 1, 131072, 64, 64);
    stats_partial<<<dim3(1, 128), 256, 0, stream>>>(BG, part, 131072, 64, 128);
    finalize_bn<<<1, 256, 0, stream>>>(part, g[1], bb[1], scales + 1 * 1024, shifts + 1 * 1024, 64, 128, 1.0 / 131072.0);
    gemm_bn<<<dim3(131072 / 64, 2), 256, 0, stream>>>(BG, w[2], A, scales + 1 * 1024, shifts + 1 * 1024, 1, 131072, 64, 128);
    stats_partial<<<dim3(2, 128), 256, 0, stream>>>(A, part, 131072, 128, 128);
    finalize_bn<<<1, 256, 0, stream>>>(part, g[2], bb[2], scales + 2 * 1024, shifts + 2 * 1024, 128, 128, 1.0 / 131072.0);
    bn_relu_max<<<(4096 * 128) / 256, 256, 0, stream>>>(A, scales + 2 * 1024, shifts + 2 * 1024, feat1, 4096, 32, 128);

    // ---------------- SA2 ----------------
    fps_fast<2, 3><<<8, 256, 0, stream>>>(nx1, 128, fps2, nx2);
    query_ball_kernel<<<(8 * 128 * 64) / 256, 256, 0, stream>>>(
        nx1, 3, 512, nx2, 8 * 128, 128, 0.16f, 64, qb2);
    group2_kernel<<<(65536 * 131) / 256, 256, 0, stream>>>(nx1, feat1, qb2, nx2, BG);

    gemm_bn<<<dim3(65536 / 64, 2), 256, 0, stream>>>(BG, w[3], A, nullptr, nullptr, 0, 65536, 131, 128);
    stats_partial<<<dim3(2, 64), 256, 0, stream>>>(A, part, 65536, 128, 64);
    finalize_bn<<<1, 256, 0, stream>>>(part, g[3], bb[3], scales + 3 * 1024, shifts + 3 * 1024, 128, 64, 1.0 / 65536.0);
    gemm_bn<<<dim3(65536 / 64, 2), 256, 0, stream>>>(A, w[4], BG, scales + 3 * 1024, shifts + 3 * 1024, 1, 65536, 128, 128);
    stats_partial<<<dim3(2, 64), 256, 0, stream>>>(BG, part, 65536, 128, 64);
    finalize_bn<<<1, 256, 0, stream>>>(part, g[4], bb[4], scales + 4 * 1024, shifts + 4 * 1024, 128, 64, 1.0 / 65536.0);
    gemm_bn<<<dim3(65536 / 64, 4), 256, 0, stream>>>(BG, w[5], A, scales + 4 * 1024, shifts + 4 * 1024, 1, 65536, 128, 256);
    stats_partial<<<dim3(4, 64), 256, 0, stream>>>(A, part, 65536, 256, 64);
    finalize_bn<<<1, 256, 0, stream>>>(part, g[5], bb[5], scales + 5 * 1024, shifts + 5 * 1024, 256, 64, 1.0 / 65536.0);
    bn_relu_max<<<(1024 * 256) / 256, 256, 0, stream>>>(A, scales + 5 * 1024, shifts + 5 * 1024, feat2, 1024, 64, 256);

    // ---------------- SA3 (group_all) ----------------
    group3_kernel<<<(1024 * 259 + 255) / 256, 256, 0, stream>>>(nx2, feat2, BG);

    gemm_bn<<<dim3(1024 / 64, 4), 256, 0, stream>>>(BG, w[6], A, nullptr, nullptr, 0, 1024, 259, 256);
    stats_partial<<<dim3(4, 1), 256, 0, stream>>>(A, part, 1024, 256, 1);
    finalize_bn<<<1, 256, 0, stream>>>(part, g[6], bb[6], scales + 6 * 1024, shifts + 6 * 1024, 256, 1, 1.0 / 1024.0);
    gemm_bn<<<dim3(1024 / 64, 8), 256, 0, stream>>>(A, w[7], BG, scales + 6 * 1024, shifts + 6 * 1024, 1, 1024, 256, 512);
    stats_partial<<<dim3(8, 1), 256, 0, stream>>>(BG, part, 1024, 512, 1);
    finalize_bn<<<2, 256, 0, stream>>>(part, g[7], bb[7], scales + 7 * 1024, shifts + 7 * 1024, 512, 1, 1.0 / 1024.0);
    gemm_bn<<<dim3(1024 / 64, 16), 256, 0, stream>>>(BG, w[8], A, scales + 7 * 1024, shifts + 7 * 1024, 1, 1024, 512, 1024);
    stats_partial<<<dim3(16, 1), 256, 0, stream>>>(A, part, 1024, 1024, 1);
    finalize_bn<<<4, 256, 0, stream>>>(part, g[8], bb[8], scales + 8 * 1024, shifts + 8 * 1024, 1024, 1, 1.0 / 1024.0);
    bn_relu_max<<<(8 * 1024) / 256, 256, 0, stream>>>(A, scales + 8 * 1024, shifts + 8 * 1024, (float*)d_out, 8, 128, 1024);
}